// Round 23
// baseline (552.284 us; speedup 1.0000x reference)
//
#include <hip/hip_runtime.h>
#include <math.h>

#define EPS 1e-5f

constexpr int Bc = 32, Cc = 256, Hc = 56, Wc = 56;
constexpr int NHc = 8, HDc = 32, WSc = 7, SSc = 3;
constexpr int NTOK = 49;
constexpr int NWIN = 64;
constexpr int Lc = Hc * Wc;                 // 3136
constexpr int Mrows = Bc * NWIN * NTOK;     // 100352
constexpr int GIMG = 16;                    // images per processing group
constexpr int NGRP = Bc / GIMG;             // 2
constexpr int ROWS_G = GIMG * Lc;           // 50176
constexpr int WIN_G = GIMG * NWIN;          // 1024

typedef short bf16x8 __attribute__((ext_vector_type(8)));
typedef float f32x4 __attribute__((ext_vector_type(4)));
typedef unsigned short u16x8 __attribute__((ext_vector_type(8)));
typedef unsigned short u16x4 __attribute__((ext_vector_type(4)));

__device__ __forceinline__ float bf2f(unsigned short u) {
    return __uint_as_float(((unsigned)u) << 16);
}
__device__ __forceinline__ unsigned short f2bf(float f) {
    unsigned x = __float_as_uint(f);
    return (unsigned short)((x + 0x7fffu + ((x >> 16) & 1u)) >> 16);  // RNE
}
__device__ __forceinline__ void gload_lds16(const void* g, void* l) {
    __builtin_amdgcn_global_load_lds(
        (const __attribute__((address_space(1))) unsigned int*)g,
        (__attribute__((address_space(3))) unsigned int*)l, 16, 0, 0);
}
// inverse of block-swizzle B' = B ^ ((B>>2)&7)
__device__ __forceinline__ void inv_swz(int bp, int& row, int& ch) {
    int b2 = ((bp >> 2) ^ (bp >> 4)) & 1;
    int b1_ = ((bp >> 1) ^ (bp >> 3)) & 1;
    int b0 = (bp ^ (bp >> 2) ^ (bp >> 4)) & 1;
    int B = (bp & ~7) | (b2 << 2) | (b1_ << 1) | b0;
    row = B >> 2; ch = B & 3;
}

// ------------------------------------------------ weight prep
__global__ __launch_bounds__(256) void k_prep(const float* __restrict__ qkv_w,
                                              const float* __restrict__ proj_w,
                                              const float* __restrict__ w1,
                                              const float* __restrict__ w2,
                                              const float* __restrict__ qb,
                                              const float* __restrict__ vb,
                                              unsigned short* __restrict__ qkv_wb,
                                              unsigned short* __restrict__ proj_wb,
                                              unsigned short* __restrict__ w1t,
                                              unsigned short* __restrict__ w2t,
                                              float* __restrict__ qkvb) {
    int i = blockIdx.x * 256 + threadIdx.x;
    if (i < 768) qkvb[i] = (i < 256) ? qb[i] : ((i < 512) ? 0.f : vb[i - 512]);
    if (i < 196608) qkv_wb[i] = f2bf(qkv_w[i]);
    if (i < 65536)  proj_wb[i] = f2bf(proj_w[i]);
    if (i < 262144) {
        int n1 = i >> 8, k1 = i & 255;       // w1: (1024, 256)
        w1t[((n1 >> 4) * 32 + (k1 >> 3)) * 128 + (n1 & 15) * 8 + (k1 & 7)] = f2bf(w1[i]);
        int n2 = i >> 10, k2 = i & 1023;     // w2: (256, 1024)
        w2t[((k2 >> 6) * 32 + (n2 >> 4) * 2 + ((k2 >> 5) & 1)) * 512 +
            ((k2 >> 3) & 3) * 128 + (n2 & 15) * 8 + (k2 & 7)] = f2bf(w2[i]);
    }
}

// ------------------------------------------------ LN1 + roll + window partition (per group)
__global__ __launch_bounds__(256) void k_ln1_part(const float* __restrict__ x,
                                                  const float* __restrict__ n1w,
                                                  const float* __restrict__ n1b,
                                                  unsigned short* __restrict__ xw,
                                                  unsigned short* __restrict__ xres,
                                                  int b0) {
    __shared__ float s[Cc * 57];
    __shared__ float mu[Wc], rs[Wc];
    int bg = blockIdx.x / Hc, h = blockIdx.x % Hc;
    int b = b0 + bg;
    int t = threadIdx.x;
    const float* xp = x + ((size_t)b * Cc) * Lc + h * Wc;
    for (int idx = t; idx < Cc * Wc; idx += 256) {
        int c = idx / Wc, w = idx % Wc;
        s[c * 57 + w] = xp[(size_t)c * Lc + w];
    }
    __syncthreads();
    int lane = t & 63, wv = t >> 6;
    for (int p = wv; p < Wc; p += 4) {
        float sum = 0.f, sq = 0.f;
        #pragma unroll
        for (int k = 0; k < 4; ++k) {
            float v = s[(lane + 64 * k) * 57 + p];
            sum += v; sq += v * v;
        }
        #pragma unroll
        for (int off = 32; off; off >>= 1) {
            sum += __shfl_xor(sum, off);
            sq  += __shfl_xor(sq, off);
        }
        if (lane == 0) {
            float m = sum / Cc;
            mu[p] = m;
            rs[p] = rsqrtf(sq / Cc - m * m + EPS);
        }
    }
    __syncthreads();
    float wc_ = n1w[t], bc_ = n1b[t];
    int hr = (h + Hc - SSc) % Hc;
    int whh = hr / WSc, th = hr % WSc;
    for (int p = 0; p < Wc; ++p) {
        float raw = s[t * 57 + p];
        xres[((size_t)bg * Lc + h * Wc + p) * Cc + t] = f2bf(raw);
        int wr = (p + Wc - SSc) % Wc;
        int www = wr / WSc, tw = wr % WSc;
        int row = (b * NWIN + whh * 8 + www) * NTOK + th * WSc + tw;
        float v = (raw - mu[p]) * rs[p] * wc_ + bc_;
        xw[(size_t)row * Cc + t] = f2bf(v);
    }
}

// ------------------------------------------------ MFMA GEMM (qkv), BK=32, global_load_lds staging
__global__ __launch_bounds__(256) void k_gemm_mfma(const unsigned short* __restrict__ A,
                                                   const unsigned short* __restrict__ W,
                                                   const float* __restrict__ bias,
                                                   unsigned short* __restrict__ outb,
                                                   int K, int Nd) {
    __shared__ unsigned short As[128 * 32];
    __shared__ unsigned short Bs[128 * 32];
    int t = threadIdx.x;
    int l = t & 63, w = t >> 6;
    int wm = w & 1, wn = w >> 1;
    int m0 = blockIdx.x * 128, n0 = blockIdx.y * 128;
    int lr = l & 15, lg = l >> 4;

    int row0, ch0, row1, ch1;
    inv_swz(w * 128 + l, row0, ch0);
    inv_swz(w * 128 + 64 + l, row1, ch1);
    const unsigned short* gA0 = A + (size_t)(m0 + row0) * K + ch0 * 8;
    const unsigned short* gA1 = A + (size_t)(m0 + row1) * K + ch1 * 8;
    const unsigned short* gB0 = W + (size_t)(n0 + row0) * K + ch0 * 8;
    const unsigned short* gB1 = W + (size_t)(n0 + row1) * K + ch1 * 8;
    unsigned short* lA0 = &As[(w * 128) * 8];
    unsigned short* lA1 = &As[(w * 128 + 64) * 8];
    unsigned short* lB0 = &Bs[(w * 128) * 8];
    unsigned short* lB1 = &Bs[(w * 128 + 64) * 8];

    f32x4 acc[4][4];
    #pragma unroll
    for (int i = 0; i < 4; ++i)
        #pragma unroll
        for (int j = 0; j < 4; ++j)
            acc[i][j] = (f32x4){0.f, 0.f, 0.f, 0.f};

    for (int kt = 0; kt < K; kt += 32) {
        gload_lds16(gA0 + kt, lA0);
        gload_lds16(gA1 + kt, lA1);
        gload_lds16(gB0 + kt, lB0);
        gload_lds16(gB1 + kt, lB1);
        __syncthreads();
        bf16x8 af[4], bfr[4];
        #pragma unroll
        for (int i = 0; i < 4; ++i) {
            int ra = wm * 64 + i * 16 + lr;
            af[i] = *(bf16x8*)&As[(ra * 32 + lg * 8) ^ ((ra & 7) << 3)];
            int rb = wn * 64 + i * 16 + lr;
            bfr[i] = *(bf16x8*)&Bs[(rb * 32 + lg * 8) ^ ((rb & 7) << 3)];
        }
        #pragma unroll
        for (int i = 0; i < 4; ++i)
            #pragma unroll
            for (int j = 0; j < 4; ++j)
                acc[i][j] = __builtin_amdgcn_mfma_f32_16x16x32_bf16(af[i], bfr[j], acc[i][j], 0, 0, 0);
        __syncthreads();
    }

    float bj[4];
    #pragma unroll
    for (int j = 0; j < 4; ++j) bj[j] = bias[n0 + wn * 64 + j * 16 + lr];
    #pragma unroll
    for (int i = 0; i < 4; ++i)
        #pragma unroll
        for (int j = 0; j < 4; ++j) {
            int col = n0 + wn * 64 + j * 16 + lr;
            #pragma unroll
            for (int r = 0; r < 4; ++r) {
                int row = m0 + wm * 64 + i * 16 + lg * 4 + r;
                outb[(size_t)row * Nd + col] = f2bf(acc[i][j][r] + bj[j]);
            }
        }
}

// ------------------------------------------------ proj GEMM BK=32 (A stride 768) + fused reverse/unshift/residual
__global__ __launch_bounds__(256) void k_gemm_proj(const unsigned short* __restrict__ A,
                                                   const unsigned short* __restrict__ W,
                                                   const float* __restrict__ bias,
                                                   const unsigned short* __restrict__ xres,
                                                   unsigned short* __restrict__ xs) {
    __shared__ unsigned short As[128 * 32];
    __shared__ unsigned short Bs[128 * 32];
    constexpr int K = 256;
    constexpr int LDA = 768;
    int t = threadIdx.x;
    int l = t & 63, w = t >> 6;
    int wm = w & 1, wn = w >> 1;
    int m0 = blockIdx.x * 128, n0 = blockIdx.y * 128;
    int lr = l & 15, lg = l >> 4;

    int row0, ch0, row1, ch1;
    inv_swz(w * 128 + l, row0, ch0);
    inv_swz(w * 128 + 64 + l, row1, ch1);
    const unsigned short* gA0 = A + (size_t)(m0 + row0) * LDA + ch0 * 8;
    const unsigned short* gA1 = A + (size_t)(m0 + row1) * LDA + ch1 * 8;
    const unsigned short* gB0 = W + (size_t)(n0 + row0) * K + ch0 * 8;
    const unsigned short* gB1 = W + (size_t)(n0 + row1) * K + ch1 * 8;
    unsigned short* lA0 = &As[(w * 128) * 8];
    unsigned short* lA1 = &As[(w * 128 + 64) * 8];
    unsigned short* lB0 = &Bs[(w * 128) * 8];
    unsigned short* lB1 = &Bs[(w * 128 + 64) * 8];

    f32x4 acc[4][4];
    #pragma unroll
    for (int i = 0; i < 4; ++i)
        #pragma unroll
        for (int j = 0; j < 4; ++j)
            acc[i][j] = (f32x4){0.f, 0.f, 0.f, 0.f};

    for (int kt = 0; kt < K; kt += 32) {
        gload_lds16(gA0 + kt, lA0);
        gload_lds16(gA1 + kt, lA1);
        gload_lds16(gB0 + kt, lB0);
        gload_lds16(gB1 + kt, lB1);
        __syncthreads();
        bf16x8 af[4], bfr[4];
        #pragma unroll
        for (int i = 0; i < 4; ++i) {
            int ra = wm * 64 + i * 16 + lr;
            af[i] = *(bf16x8*)&As[(ra * 32 + lg * 8) ^ ((ra & 7) << 3)];
            int rb = wn * 64 + i * 16 + lr;
            bfr[i] = *(bf16x8*)&Bs[(rb * 32 + lg * 8) ^ ((rb & 7) << 3)];
        }
        #pragma unroll
        for (int i = 0; i < 4; ++i)
            #pragma unroll
            for (int j = 0; j < 4; ++j)
                acc[i][j] = __builtin_amdgcn_mfma_f32_16x16x32_bf16(af[i], bfr[j], acc[i][j], 0, 0, 0);
        __syncthreads();
    }

    float bj[4];
    #pragma unroll
    for (int j = 0; j < 4; ++j) bj[j] = bias[n0 + wn * 64 + j * 16 + lr];
    #pragma unroll
    for (int i = 0; i < 4; ++i)
        #pragma unroll
        for (int j = 0; j < 4; ++j) {
            int col = n0 + wn * 64 + j * 16 + lr;
            #pragma unroll
            for (int r = 0; r < 4; ++r) {
                int row = m0 + wm * 64 + i * 16 + lg * 4 + r;   // group-local window row
                int wl = row / NTOK, tok = row - wl * NTOK;
                int bg = wl >> 6, wi = wl & 63;
                int hr = (wi >> 3) * 7 + tok / 7;
                int wr = (wi & 7) * 7 + tok % 7;
                int hh = hr + SSc; if (hh >= Hc) hh -= Hc;
                int ww = wr + SSc; if (ww >= Wc) ww -= Wc;
                size_t didx = ((size_t)bg * Lc + hh * Wc + ww) * Cc + col;
                float res = bf2f(xres[didx]);
                xs[didx] = f2bf(res + acc[i][j][r] + bj[j]);
            }
        }
}

// ------------------------------------------------ window attention v3 (MFMA, 1 wave per window-head)
// Output written IN PLACE over the Q columns (cols hh*32..+32) of this window's qkv rows.
__global__ __launch_bounds__(256) void k_attn(unsigned short* __restrict__ qkv,
                                              const float* __restrict__ rpb) {
    __shared__ unsigned short lds[4 * 6144 + 1352];
    unsigned short* rpbs = &lds[4 * 6144];
    int t = threadIdx.x;
    int w = t >> 6, l = t & 63;
    int lr = l & 15, lg = l >> 4;
    unsigned short* wl = &lds[w * 6144];
    unsigned short* Qs = wl;
    unsigned short* Ks = wl + 2048;
    unsigned short* Pm = wl;            // overlays Q/K after QK MFMA
    unsigned short* Vt = wl + 4096;

    for (int i = t; i < 1352; i += 256) rpbs[i] = f2bf(rpb[i]);

    int gid = blockIdx.x * 4 + w;
    int b_ = gid >> 3, hh = gid & 7;
    unsigned short* base = qkv + (size_t)b_ * NTOK * 768 + hh * HDc;

    {
        int j = l;
        u16x8 vq[4], vk[4], vv[4];
        if (j < NTOK) {
            const unsigned short* rp = base + j * 768;
            #pragma unroll
            for (int s = 0; s < 4; ++s) {
                vq[s] = *(const u16x8*)(rp + s * 8);
                vk[s] = *(const u16x8*)(rp + 256 + s * 8);
                vv[s] = *(const u16x8*)(rp + 512 + s * 8);
            }
        } else {
            u16x8 z = {0, 0, 0, 0, 0, 0, 0, 0};
            #pragma unroll
            for (int s = 0; s < 4; ++s) { vq[s] = z; vk[s] = z; vv[s] = z; }
        }
        #pragma unroll
        for (int s = 0; s < 4; ++s) {
            int off = (j * 32 + s * 8) ^ ((j & 7) << 3);
            *(u16x8*)&Qs[off] = vq[s];
            *(u16x8*)&Ks[off] = vk[s];
        }
        #pragma unroll
        for (int s = 0; s < 4; ++s)
            #pragma unroll
            for (int e = 0; e < 8; ++e) {
                int d = s * 8 + e;
                Vt[d * 64 + (j ^ ((d & 7) << 3))] = ((unsigned short*)&vv[s])[e];
            }
    }
    __syncthreads();

    bf16x8 aq[4], bk[4];
    #pragma unroll
    for (int mt = 0; mt < 4; ++mt) {
        int row = mt * 16 + lr;
        int off = (row * 32 + lg * 8) ^ ((row & 7) << 3);
        aq[mt] = *(bf16x8*)&Qs[off];
        bk[mt] = *(bf16x8*)&Ks[off];
    }
    f32x4 sc[4][4];
    __builtin_amdgcn_s_setprio(1);
    #pragma unroll
    for (int mt = 0; mt < 4; ++mt)
        #pragma unroll
        for (int nt = 0; nt < 4; ++nt)
            sc[mt][nt] = __builtin_amdgcn_mfma_f32_16x16x32_bf16(
                aq[mt], bk[nt], (f32x4){0.f, 0.f, 0.f, 0.f}, 0, 0, 0);
    __builtin_amdgcn_s_setprio(0);

    const float scale = 0.17677669529663687f;
    int wi = b_ & 63, wh = wi >> 3, wwc = wi & 7;
    int jh[4], jw[4], ridJ[4];
    #pragma unroll
    for (int nt = 0; nt < 4; ++nt) {
        int j = nt * 16 + lr;
        jh[nt] = j / 7; jw[nt] = j - jh[nt] * 7;
        int gh = wh * 7 + jh[nt], gw = wwc * 7 + jw[nt];
        int rh = gh < 49 ? 0 : (gh < 53 ? 1 : 2);
        int rw = gw < 49 ? 0 : (gw < 53 ? 1 : 2);
        ridJ[nt] = rh * 3 + rw;
    }

    float rowrcp[4][4];
    #pragma unroll
    for (int mt = 0; mt < 4; ++mt) {
        #pragma unroll
        for (int r = 0; r < 4; ++r) {
            int i = mt * 16 + lg * 4 + r;
            int ih = i / 7, iw = i - ih * 7;
            int gh = wh * 7 + ih, gw = wwc * 7 + iw;
            int rhI = gh < 49 ? 0 : (gh < 53 ? 1 : 2);
            int rwI = gw < 49 ? 0 : (gw < 53 ? 1 : 2);
            int ridI = rhI * 3 + rwI;
            bool ivalid = (i < NTOK);
            float vals[4];
            float vmax = -1e30f;
            #pragma unroll
            for (int nt = 0; nt < 4; ++nt) {
                int j = nt * 16 + lr;
                float v = -1e30f;
                if (ivalid && j < NTOK) {
                    int rpi = (ih - jh[nt] + 6) * 13 + (iw - jw[nt] + 6);
                    float bv = bf2f(rpbs[rpi * 8 + hh]);
                    float msk = (ridI == ridJ[nt]) ? 0.f : -100.f;
                    v = sc[mt][nt][r] * scale + bv + msk;
                }
                vals[nt] = v;
                vmax = fmaxf(vmax, v);
            }
            #pragma unroll
            for (int off = 1; off < 16; off <<= 1)
                vmax = fmaxf(vmax, __shfl_xor(vmax, off));
            float s = 0.f;
            unsigned short pb[4];
            #pragma unroll
            for (int nt = 0; nt < 4; ++nt) {
                float e = (vals[nt] > -1e29f) ? __expf(vals[nt] - vmax) : 0.f;
                s += e;
                pb[nt] = f2bf(e);
            }
            #pragma unroll
            for (int off = 1; off < 16; off <<= 1)
                s += __shfl_xor(s, off);
            rowrcp[mt][r] = 1.f / s;
            #pragma unroll
            for (int nt = 0; nt < 4; ++nt) {
                int j = nt * 16 + lr;
                Pm[(i * 64 + j) ^ ((i & 7) << 3)] = pb[nt];
            }
        }
    }

    f32x4 o[4][2];
    #pragma unroll
    for (int mt = 0; mt < 4; ++mt)
        #pragma unroll
        for (int nt = 0; nt < 2; ++nt)
            o[mt][nt] = (f32x4){0.f, 0.f, 0.f, 0.f};
    #pragma unroll
    for (int ks = 0; ks < 2; ++ks) {
        bf16x8 ap[4], bv2[2];
        #pragma unroll
        for (int mt = 0; mt < 4; ++mt) {
            int row = mt * 16 + lr;
            ap[mt] = *(bf16x8*)&Pm[(row * 64 + ks * 32 + lg * 8) ^ ((row & 7) << 3)];
        }
        #pragma unroll
        for (int nt = 0; nt < 2; ++nt) {
            int n = nt * 16 + lr;
            bv2[nt] = *(bf16x8*)&Vt[(n * 64 + ks * 32 + lg * 8) ^ ((n & 7) << 3)];
        }
        __builtin_amdgcn_s_setprio(1);
        #pragma unroll
        for (int mt = 0; mt < 4; ++mt)
            #pragma unroll
            for (int nt = 0; nt < 2; ++nt)
                o[mt][nt] = __builtin_amdgcn_mfma_f32_16x16x32_bf16(ap[mt], bv2[nt], o[mt][nt], 0, 0, 0);
        __builtin_amdgcn_s_setprio(0);
    }

    // in-place store into the Q columns of this (window, head)
    #pragma unroll
    for (int mt = 0; mt < 4; ++mt)
        #pragma unroll
        for (int r = 0; r < 4; ++r) {
            int i = mt * 16 + lg * 4 + r;
            if (i < NTOK) {
                float rc = rowrcp[mt][r];
                #pragma unroll
                for (int nt = 0; nt < 2; ++nt) {
                    int d = nt * 16 + lr;
                    qkv[((size_t)b_ * NTOK + i) * 768 + hh * HDc + d] = f2bf(o[mt][nt][r] * rc);
                }
            }
        }
}

// ------------------------------------------------ fused LN2 + MLP v9+T5 + residual + NCHW out
// 64 rows/block, 512 threads (8 waves). Wave (wm=w>>1) owns 16 rows, (wn=w&1) a 128-col half.
// v9 structure (session best, 238us) + s_setprio(1) around fc1/fc2 MFMA clusters: with
// ~1.6 co-resident blocks/CU at independent phases, MFMA waves get scheduler priority
// over the other block's staging loads (T5 mechanism; phase-diverse regime per m191).
#define HIDX(m, c) (((m) * 64 + (c)) ^ (((m) & 7) << 3))
__global__ __launch_bounds__(512) void k_mlp_fused(const unsigned short* __restrict__ xs,
                                                   const float* __restrict__ n2w,
                                                   const float* __restrict__ n2b,
                                                   const unsigned short* __restrict__ w1t,
                                                   const float* __restrict__ b1,
                                                   const unsigned short* __restrict__ w2t,
                                                   const float* __restrict__ b2,
                                                   float* __restrict__ out) {
    __shared__ unsigned short w1s[16384];   // 32KB
    __shared__ unsigned short w2s[16384];   // 32KB
    __shared__ unsigned short hid[4096];    // 64m x 64c, swizzled (8KB)
    int t = threadIdx.x;
    int l = t & 63, w = t >> 6;
    int wm = w >> 1, wn = w & 1;
    int lr = l & 15, lg = l >> 4;
    int m0 = blockIdx.x * 64;

    // ---- Phase A: LN2 into registers (row = wm*16+lr; 4 lanes (lg) per row)
    bf16x8 xf[8];
    {
        int row = m0 + wm * 16 + lr;
        const unsigned short* xrow = xs + (size_t)row * Cc;
        u16x8 raw[8];
        float sum = 0.f, sq = 0.f;
        #pragma unroll
        for (int ks = 0; ks < 8; ++ks) {
            raw[ks] = *(const u16x8*)(xrow + ks * 32 + lg * 8);
            #pragma unroll
            for (int e = 0; e < 8; ++e) {
                float f = bf2f(raw[ks][e]);
                sum += f; sq += f * f;
            }
        }
        sum += __shfl_xor(sum, 16); sq += __shfl_xor(sq, 16);
        sum += __shfl_xor(sum, 32); sq += __shfl_xor(sq, 32);
        float mu = sum / Cc;
        float rsg = rsqrtf(sq / Cc - mu * mu + EPS);
        #pragma unroll
        for (int ks = 0; ks < 8; ++ks) {
            #pragma unroll
            for (int e = 0; e < 8; ++e) {
                int c = ks * 32 + lg * 8 + e;
                float nv = (bf2f(raw[ks][e]) - mu) * rsg * n2w[c] + n2b[c];
                ((unsigned short*)&xf[ks])[e] = f2bf(nv);
            }
        }
    }

    f32x4 acc2[8];
    #pragma unroll
    for (int nf = 0; nf < 8; ++nf)
        acc2[nf] = (f32x4){0.f, 0.f, 0.f, 0.f};

    // prefetch chunk 0 (both weight buffers)
    u16x8 p1[4], p2[4];
    #pragma unroll
    for (int i = 0; i < 4; ++i) {
        int idx = (i * 512 + t) * 8;
        p1[i] = *(const u16x8*)(w1t + idx);
        p2[i] = *(const u16x8*)(w2t + idx);
    }

    for (int ch = 0; ch < 16; ++ch) {
        // ---- commit prefetched chunk to LDS
        #pragma unroll
        for (int i = 0; i < 4; ++i) {
            int idx = (i * 512 + t) * 8;
            *(u16x8*)&w1s[idx] = p1[i];
            *(u16x8*)&w2s[idx] = p2[i];
        }
        __syncthreads();
        // ---- issue prefetch for chunk ch+1 (completes under fc1+fc2)
        if (ch < 15) {
            const unsigned short* n1 = w1t + (ch + 1) * 16384;
            const unsigned short* n2 = w2t + (ch + 1) * 16384;
            #pragma unroll
            for (int i = 0; i < 4; ++i) {
                int idx = (i * 512 + t) * 8;
                p1[i] = *(const u16x8*)(n1 + idx);
                p2[i] = *(const u16x8*)(n2 + idx);
            }
        }
        // ---- fc1 (transposed): D[h][m]; wave: h-tiles {2wn,2wn+1}, its own m-frag (wm)
        {
            f32x4 acc1[2];
            acc1[0] = (f32x4){0.f, 0.f, 0.f, 0.f};
            acc1[1] = (f32x4){0.f, 0.f, 0.f, 0.f};
            __builtin_amdgcn_s_setprio(1);
            #pragma unroll
            for (int ks = 0; ks < 8; ++ks) {
                #pragma unroll
                for (int ht = 0; ht < 2; ++ht) {
                    bf16x8 wfr = *(const bf16x8*)&w1s[(wn * 2 + ht) * 4096 + ks * 512 + l * 8];
                    acc1[ht] = __builtin_amdgcn_mfma_f32_16x16x32_bf16(wfr, xf[ks], acc1[ht], 0, 0, 0);
                }
            }
            __builtin_amdgcn_s_setprio(0);
            #pragma unroll
            for (int ht = 0; ht < 2; ++ht) {
                float b1v[4];
                #pragma unroll
                for (int r = 0; r < 4; ++r)
                    b1v[r] = b1[ch * 64 + (wn * 2 + ht) * 16 + lg * 4 + r];
                u16x4 pk;
                #pragma unroll
                for (int r = 0; r < 4; ++r)
                    pk[r] = f2bf(fmaxf(acc1[ht][r] + b1v[r], 0.f));
                int m = wm * 16 + lr;
                int off = m * 64 + ((((wn * 2 + ht) * 16) + lg * 4) ^ ((m & 7) << 3));
                *(u16x4*)&hid[off] = pk;
            }
        }
        __syncthreads();
        // ---- fc2 partial over this chunk's 64 h-dims (w2 from LDS)
        {
            bf16x8 a[2];
            #pragma unroll
            for (int ks = 0; ks < 2; ++ks) {
                int m = wm * 16 + lr;
                a[ks] = *(const bf16x8*)&hid[HIDX(m, ks * 32 + lg * 8)];
            }
            __builtin_amdgcn_s_setprio(1);
            #pragma unroll
            for (int ks = 0; ks < 2; ++ks)
                #pragma unroll
                for (int nf = 0; nf < 8; ++nf) {
                    int nt = wn * 8 + nf;
                    bf16x8 bfr = *(const bf16x8*)&w2s[(nt * 2 + ks) * 512 + l * 8];
                    acc2[nf] = __builtin_amdgcn_mfma_f32_16x16x32_bf16(a[ks], bfr, acc2[nf], 0, 0, 0);
                }
            __builtin_amdgcn_s_setprio(0);
        }
        __syncthreads();
    }

    // ---- epilogue: + b2 + residual, NCHW store (64 | Lc: no image straddle)
    int b0i = m0 / Lc, l0 = m0 % Lc;
    #pragma unroll
    for (int nf = 0; nf < 8; ++nf) {
        int c = wn * 128 + nf * 16 + lr;
        float b2c = b2[c];
        #pragma unroll
        for (int r = 0; r < 4; ++r) {
            int m = wm * 16 + lg * 4 + r;
            float res = bf2f(xs[(size_t)(m0 + m) * Cc + c]);
            out[((size_t)b0i * Cc + c) * Lc + l0 + m] = acc2[nf][r] + b2c + res;
        }
    }
}

// ----------------------------------------------------------------- launch
extern "C" void kernel_launch(void* const* d_in, const int* in_sizes, int n_in,
                              void* d_out, int out_size, void* d_ws, size_t ws_size,
                              hipStream_t stream) {
    const float* x      = (const float*)d_in[0];
    const float* qkv_w  = (const float*)d_in[1];
    const float* q_bias = (const float*)d_in[2];
    const float* v_bias = (const float*)d_in[3];
    const float* proj_w = (const float*)d_in[4];
    const float* proj_b = (const float*)d_in[5];
    const float* rpb    = (const float*)d_in[6];
    const float* n1w    = (const float*)d_in[7];
    const float* n1b    = (const float*)d_in[8];
    const float* n2w    = (const float*)d_in[9];
    const float* n2b    = (const float*)d_in[10];
    const float* w1     = (const float*)d_in[11];
    const float* b1     = (const float*)d_in[12];
    const float* w2     = (const float*)d_in[13];
    const float* b2     = (const float*)d_in[14];

    char* ws = (char*)d_ws;
    const size_t SZ_BF16 = (size_t)Mrows * Cc * 2;
    unsigned short* xw      = (unsigned short*)ws;          // xw, later xs (b,l,c)
    float*          qkvb    = (float*)(ws + SZ_BF16);
    unsigned short* qkv_wb  = (unsigned short*)(ws + SZ_BF16 + 3072);
    unsigned short* proj_wb = qkv_wb + 196608;
    unsigned short* w1t     = proj_wb + 65536;
    unsigned short* w2t     = w1t + 262144;

    // d_out scratch (exact fit; fully overwritten by k_mlp_fused):
    //   [0, 77,070,336)             qkv_s bf16 (50176 x 768); attn writes output in place over Q cols
    //   [77,070,336, 102,760,448)   xres bf16 (50176 x 256)
    unsigned short* qkv_s  = (unsigned short*)d_out;
    unsigned short* xres_s = qkv_s + (size_t)ROWS_G * 768;

    k_prep<<<1024, 256, 0, stream>>>(qkv_w, proj_w, w1, w2, q_bias, v_bias,
                                     qkv_wb, proj_wb, w1t, w2t, qkvb);

    for (int g = 0; g < NGRP; ++g) {
        unsigned short* xw_g = xw + (size_t)g * ROWS_G * Cc;
        k_ln1_part<<<GIMG * Hc, 256, 0, stream>>>(x, n1w, n1b, xw, xres_s, g * GIMG);
        k_gemm_mfma<<<dim3(ROWS_G / 128, 768 / 128), 256, 0, stream>>>(
            xw_g, qkv_wb, qkvb, qkv_s, 256, 768);
        k_attn<<<WIN_G * NHc / 4, 256, 0, stream>>>(qkv_s, rpb);
        k_gemm_proj<<<dim3(ROWS_G / 128, 2), 256, 0, stream>>>(
            qkv_s, proj_wb, proj_b, xres_s, xw_g);
    }

    k_mlp_fused<<<Mrows / 64, 512, 0, stream>>>(xw, n2w, n2b, w1t, b1, w2t, b2,
                                                (float*)d_out);
}

// Round 24
// 514.482 us; speedup vs baseline: 1.0735x; 1.0735x over previous
//
#include <hip/hip_runtime.h>
#include <math.h>

#define EPS 1e-5f

constexpr int Bc = 32, Cc = 256, Hc = 56, Wc = 56;
constexpr int NHc = 8, HDc = 32, WSc = 7, SSc = 3;
constexpr int NTOK = 49;
constexpr int NWIN = 64;
constexpr int Lc = Hc * Wc;                 // 3136
constexpr int Mrows = Bc * NWIN * NTOK;     // 100352
constexpr int GIMG = 16;                    // images per processing group
constexpr int NGRP = Bc / GIMG;             // 2
constexpr int ROWS_G = GIMG * Lc;           // 50176
constexpr int WIN_G = GIMG * NWIN;          // 1024

typedef short bf16x8 __attribute__((ext_vector_type(8)));
typedef float f32x4 __attribute__((ext_vector_type(4)));
typedef unsigned short u16x8 __attribute__((ext_vector_type(8)));
typedef unsigned short u16x4 __attribute__((ext_vector_type(4)));

__device__ __forceinline__ float bf2f(unsigned short u) {
    return __uint_as_float(((unsigned)u) << 16);
}
__device__ __forceinline__ unsigned short f2bf(float f) {
    unsigned x = __float_as_uint(f);
    return (unsigned short)((x + 0x7fffu + ((x >> 16) & 1u)) >> 16);  // RNE
}
__device__ __forceinline__ void gload_lds16(const void* g, void* l) {
    __builtin_amdgcn_global_load_lds(
        (const __attribute__((address_space(1))) unsigned int*)g,
        (__attribute__((address_space(3))) unsigned int*)l, 16, 0, 0);
}
// inverse of block-swizzle B' = B ^ ((B>>2)&7)
__device__ __forceinline__ void inv_swz(int bp, int& row, int& ch) {
    int b2 = ((bp >> 2) ^ (bp >> 4)) & 1;
    int b1_ = ((bp >> 1) ^ (bp >> 3)) & 1;
    int b0 = (bp ^ (bp >> 2) ^ (bp >> 4)) & 1;
    int B = (bp & ~7) | (b2 << 2) | (b1_ << 1) | b0;
    row = B >> 2; ch = B & 3;
}

// ------------------------------------------------ weight prep
__global__ __launch_bounds__(256) void k_prep(const float* __restrict__ qkv_w,
                                              const float* __restrict__ proj_w,
                                              const float* __restrict__ w1,
                                              const float* __restrict__ w2,
                                              const float* __restrict__ qb,
                                              const float* __restrict__ vb,
                                              unsigned short* __restrict__ qkv_wb,
                                              unsigned short* __restrict__ proj_wb,
                                              unsigned short* __restrict__ w1t,
                                              unsigned short* __restrict__ w2t,
                                              float* __restrict__ qkvb) {
    int i = blockIdx.x * 256 + threadIdx.x;
    if (i < 768) qkvb[i] = (i < 256) ? qb[i] : ((i < 512) ? 0.f : vb[i - 512]);
    if (i < 196608) qkv_wb[i] = f2bf(qkv_w[i]);
    if (i < 65536)  proj_wb[i] = f2bf(proj_w[i]);
    if (i < 262144) {
        int n1 = i >> 8, k1 = i & 255;       // w1: (1024, 256)
        w1t[((n1 >> 4) * 32 + (k1 >> 3)) * 128 + (n1 & 15) * 8 + (k1 & 7)] = f2bf(w1[i]);
        int n2 = i >> 10, k2 = i & 1023;     // w2: (256, 1024)
        w2t[((k2 >> 6) * 32 + (n2 >> 4) * 2 + ((k2 >> 5) & 1)) * 512 +
            ((k2 >> 3) & 3) * 128 + (n2 & 15) * 8 + (k2 & 7)] = f2bf(w2[i]);
    }
}

// ------------------------------------------------ LN1 + roll + window partition (per group)
__global__ __launch_bounds__(256) void k_ln1_part(const float* __restrict__ x,
                                                  const float* __restrict__ n1w,
                                                  const float* __restrict__ n1b,
                                                  unsigned short* __restrict__ xw,
                                                  unsigned short* __restrict__ xres,
                                                  int b0) {
    __shared__ float s[Cc * 57];
    __shared__ float mu[Wc], rs[Wc];
    int bg = blockIdx.x / Hc, h = blockIdx.x % Hc;
    int b = b0 + bg;
    int t = threadIdx.x;
    const float* xp = x + ((size_t)b * Cc) * Lc + h * Wc;
    for (int idx = t; idx < Cc * Wc; idx += 256) {
        int c = idx / Wc, w = idx % Wc;
        s[c * 57 + w] = xp[(size_t)c * Lc + w];
    }
    __syncthreads();
    int lane = t & 63, wv = t >> 6;
    for (int p = wv; p < Wc; p += 4) {
        float sum = 0.f, sq = 0.f;
        #pragma unroll
        for (int k = 0; k < 4; ++k) {
            float v = s[(lane + 64 * k) * 57 + p];
            sum += v; sq += v * v;
        }
        #pragma unroll
        for (int off = 32; off; off >>= 1) {
            sum += __shfl_xor(sum, off);
            sq  += __shfl_xor(sq, off);
        }
        if (lane == 0) {
            float m = sum / Cc;
            mu[p] = m;
            rs[p] = rsqrtf(sq / Cc - m * m + EPS);
        }
    }
    __syncthreads();
    float wc_ = n1w[t], bc_ = n1b[t];
    int hr = (h + Hc - SSc) % Hc;
    int whh = hr / WSc, th = hr % WSc;
    for (int p = 0; p < Wc; ++p) {
        float raw = s[t * 57 + p];
        xres[((size_t)bg * Lc + h * Wc + p) * Cc + t] = f2bf(raw);
        int wr = (p + Wc - SSc) % Wc;
        int www = wr / WSc, tw = wr % WSc;
        int row = (b * NWIN + whh * 8 + www) * NTOK + th * WSc + tw;
        float v = (raw - mu[p]) * rs[p] * wc_ + bc_;
        xw[(size_t)row * Cc + t] = f2bf(v);
    }
}

// ------------------------------------------------ MFMA GEMM (qkv), BK=32, global_load_lds staging
__global__ __launch_bounds__(256) void k_gemm_mfma(const unsigned short* __restrict__ A,
                                                   const unsigned short* __restrict__ W,
                                                   const float* __restrict__ bias,
                                                   unsigned short* __restrict__ outb,
                                                   int K, int Nd) {
    __shared__ unsigned short As[128 * 32];
    __shared__ unsigned short Bs[128 * 32];
    int t = threadIdx.x;
    int l = t & 63, w = t >> 6;
    int wm = w & 1, wn = w >> 1;
    int m0 = blockIdx.x * 128, n0 = blockIdx.y * 128;
    int lr = l & 15, lg = l >> 4;

    int row0, ch0, row1, ch1;
    inv_swz(w * 128 + l, row0, ch0);
    inv_swz(w * 128 + 64 + l, row1, ch1);
    const unsigned short* gA0 = A + (size_t)(m0 + row0) * K + ch0 * 8;
    const unsigned short* gA1 = A + (size_t)(m0 + row1) * K + ch1 * 8;
    const unsigned short* gB0 = W + (size_t)(n0 + row0) * K + ch0 * 8;
    const unsigned short* gB1 = W + (size_t)(n0 + row1) * K + ch1 * 8;
    unsigned short* lA0 = &As[(w * 128) * 8];
    unsigned short* lA1 = &As[(w * 128 + 64) * 8];
    unsigned short* lB0 = &Bs[(w * 128) * 8];
    unsigned short* lB1 = &Bs[(w * 128 + 64) * 8];

    f32x4 acc[4][4];
    #pragma unroll
    for (int i = 0; i < 4; ++i)
        #pragma unroll
        for (int j = 0; j < 4; ++j)
            acc[i][j] = (f32x4){0.f, 0.f, 0.f, 0.f};

    for (int kt = 0; kt < K; kt += 32) {
        gload_lds16(gA0 + kt, lA0);
        gload_lds16(gA1 + kt, lA1);
        gload_lds16(gB0 + kt, lB0);
        gload_lds16(gB1 + kt, lB1);
        __syncthreads();
        bf16x8 af[4], bfr[4];
        #pragma unroll
        for (int i = 0; i < 4; ++i) {
            int ra = wm * 64 + i * 16 + lr;
            af[i] = *(bf16x8*)&As[(ra * 32 + lg * 8) ^ ((ra & 7) << 3)];
            int rb = wn * 64 + i * 16 + lr;
            bfr[i] = *(bf16x8*)&Bs[(rb * 32 + lg * 8) ^ ((rb & 7) << 3)];
        }
        #pragma unroll
        for (int i = 0; i < 4; ++i)
            #pragma unroll
            for (int j = 0; j < 4; ++j)
                acc[i][j] = __builtin_amdgcn_mfma_f32_16x16x32_bf16(af[i], bfr[j], acc[i][j], 0, 0, 0);
        __syncthreads();
    }

    float bj[4];
    #pragma unroll
    for (int j = 0; j < 4; ++j) bj[j] = bias[n0 + wn * 64 + j * 16 + lr];
    #pragma unroll
    for (int i = 0; i < 4; ++i)
        #pragma unroll
        for (int j = 0; j < 4; ++j) {
            int col = n0 + wn * 64 + j * 16 + lr;
            #pragma unroll
            for (int r = 0; r < 4; ++r) {
                int row = m0 + wm * 64 + i * 16 + lg * 4 + r;
                outb[(size_t)row * Nd + col] = f2bf(acc[i][j][r] + bj[j]);
            }
        }
}

// ------------------------------------------------ proj GEMM BK=32 (A stride 768) + fused reverse/unshift/residual
__global__ __launch_bounds__(256) void k_gemm_proj(const unsigned short* __restrict__ A,
                                                   const unsigned short* __restrict__ W,
                                                   const float* __restrict__ bias,
                                                   const unsigned short* __restrict__ xres,
                                                   unsigned short* __restrict__ xs) {
    __shared__ unsigned short As[128 * 32];
    __shared__ unsigned short Bs[128 * 32];
    constexpr int K = 256;
    constexpr int LDA = 768;
    int t = threadIdx.x;
    int l = t & 63, w = t >> 6;
    int wm = w & 1, wn = w >> 1;
    int m0 = blockIdx.x * 128, n0 = blockIdx.y * 128;
    int lr = l & 15, lg = l >> 4;

    int row0, ch0, row1, ch1;
    inv_swz(w * 128 + l, row0, ch0);
    inv_swz(w * 128 + 64 + l, row1, ch1);
    const unsigned short* gA0 = A + (size_t)(m0 + row0) * LDA + ch0 * 8;
    const unsigned short* gA1 = A + (size_t)(m0 + row1) * LDA + ch1 * 8;
    const unsigned short* gB0 = W + (size_t)(n0 + row0) * K + ch0 * 8;
    const unsigned short* gB1 = W + (size_t)(n0 + row1) * K + ch1 * 8;
    unsigned short* lA0 = &As[(w * 128) * 8];
    unsigned short* lA1 = &As[(w * 128 + 64) * 8];
    unsigned short* lB0 = &Bs[(w * 128) * 8];
    unsigned short* lB1 = &Bs[(w * 128 + 64) * 8];

    f32x4 acc[4][4];
    #pragma unroll
    for (int i = 0; i < 4; ++i)
        #pragma unroll
        for (int j = 0; j < 4; ++j)
            acc[i][j] = (f32x4){0.f, 0.f, 0.f, 0.f};

    for (int kt = 0; kt < K; kt += 32) {
        gload_lds16(gA0 + kt, lA0);
        gload_lds16(gA1 + kt, lA1);
        gload_lds16(gB0 + kt, lB0);
        gload_lds16(gB1 + kt, lB1);
        __syncthreads();
        bf16x8 af[4], bfr[4];
        #pragma unroll
        for (int i = 0; i < 4; ++i) {
            int ra = wm * 64 + i * 16 + lr;
            af[i] = *(bf16x8*)&As[(ra * 32 + lg * 8) ^ ((ra & 7) << 3)];
            int rb = wn * 64 + i * 16 + lr;
            bfr[i] = *(bf16x8*)&Bs[(rb * 32 + lg * 8) ^ ((rb & 7) << 3)];
        }
        #pragma unroll
        for (int i = 0; i < 4; ++i)
            #pragma unroll
            for (int j = 0; j < 4; ++j)
                acc[i][j] = __builtin_amdgcn_mfma_f32_16x16x32_bf16(af[i], bfr[j], acc[i][j], 0, 0, 0);
        __syncthreads();
    }

    float bj[4];
    #pragma unroll
    for (int j = 0; j < 4; ++j) bj[j] = bias[n0 + wn * 64 + j * 16 + lr];
    #pragma unroll
    for (int i = 0; i < 4; ++i)
        #pragma unroll
        for (int j = 0; j < 4; ++j) {
            int col = n0 + wn * 64 + j * 16 + lr;
            #pragma unroll
            for (int r = 0; r < 4; ++r) {
                int row = m0 + wm * 64 + i * 16 + lg * 4 + r;   // group-local window row
                int wl = row / NTOK, tok = row - wl * NTOK;
                int bg = wl >> 6, wi = wl & 63;
                int hr = (wi >> 3) * 7 + tok / 7;
                int wr = (wi & 7) * 7 + tok % 7;
                int hh = hr + SSc; if (hh >= Hc) hh -= Hc;
                int ww = wr + SSc; if (ww >= Wc) ww -= Wc;
                size_t didx = ((size_t)bg * Lc + hh * Wc + ww) * Cc + col;
                float res = bf2f(xres[didx]);
                xs[didx] = f2bf(res + acc[i][j][r] + bj[j]);
            }
        }
}

// ------------------------------------------------ window attention v3 (MFMA, 1 wave per window-head)
// Output written IN PLACE over the Q columns (cols hh*32..+32) of this window's qkv rows.
__global__ __launch_bounds__(256) void k_attn(unsigned short* __restrict__ qkv,
                                              const float* __restrict__ rpb) {
    __shared__ unsigned short lds[4 * 6144 + 1352];
    unsigned short* rpbs = &lds[4 * 6144];
    int t = threadIdx.x;
    int w = t >> 6, l = t & 63;
    int lr = l & 15, lg = l >> 4;
    unsigned short* wl = &lds[w * 6144];
    unsigned short* Qs = wl;
    unsigned short* Ks = wl + 2048;
    unsigned short* Pm = wl;            // overlays Q/K after QK MFMA
    unsigned short* Vt = wl + 4096;

    for (int i = t; i < 1352; i += 256) rpbs[i] = f2bf(rpb[i]);

    int gid = blockIdx.x * 4 + w;
    int b_ = gid >> 3, hh = gid & 7;
    unsigned short* base = qkv + (size_t)b_ * NTOK * 768 + hh * HDc;

    {
        int j = l;
        u16x8 vq[4], vk[4], vv[4];
        if (j < NTOK) {
            const unsigned short* rp = base + j * 768;
            #pragma unroll
            for (int s = 0; s < 4; ++s) {
                vq[s] = *(const u16x8*)(rp + s * 8);
                vk[s] = *(const u16x8*)(rp + 256 + s * 8);
                vv[s] = *(const u16x8*)(rp + 512 + s * 8);
            }
        } else {
            u16x8 z = {0, 0, 0, 0, 0, 0, 0, 0};
            #pragma unroll
            for (int s = 0; s < 4; ++s) { vq[s] = z; vk[s] = z; vv[s] = z; }
        }
        #pragma unroll
        for (int s = 0; s < 4; ++s) {
            int off = (j * 32 + s * 8) ^ ((j & 7) << 3);
            *(u16x8*)&Qs[off] = vq[s];
            *(u16x8*)&Ks[off] = vk[s];
        }
        #pragma unroll
        for (int s = 0; s < 4; ++s)
            #pragma unroll
            for (int e = 0; e < 8; ++e) {
                int d = s * 8 + e;
                Vt[d * 64 + (j ^ ((d & 7) << 3))] = ((unsigned short*)&vv[s])[e];
            }
    }
    __syncthreads();

    bf16x8 aq[4], bk[4];
    #pragma unroll
    for (int mt = 0; mt < 4; ++mt) {
        int row = mt * 16 + lr;
        int off = (row * 32 + lg * 8) ^ ((row & 7) << 3);
        aq[mt] = *(bf16x8*)&Qs[off];
        bk[mt] = *(bf16x8*)&Ks[off];
    }
    f32x4 sc[4][4];
    #pragma unroll
    for (int mt = 0; mt < 4; ++mt)
        #pragma unroll
        for (int nt = 0; nt < 4; ++nt)
            sc[mt][nt] = __builtin_amdgcn_mfma_f32_16x16x32_bf16(
                aq[mt], bk[nt], (f32x4){0.f, 0.f, 0.f, 0.f}, 0, 0, 0);

    const float scale = 0.17677669529663687f;
    int wi = b_ & 63, wh = wi >> 3, wwc = wi & 7;
    int jh[4], jw[4], ridJ[4];
    #pragma unroll
    for (int nt = 0; nt < 4; ++nt) {
        int j = nt * 16 + lr;
        jh[nt] = j / 7; jw[nt] = j - jh[nt] * 7;
        int gh = wh * 7 + jh[nt], gw = wwc * 7 + jw[nt];
        int rh = gh < 49 ? 0 : (gh < 53 ? 1 : 2);
        int rw = gw < 49 ? 0 : (gw < 53 ? 1 : 2);
        ridJ[nt] = rh * 3 + rw;
    }

    float rowrcp[4][4];
    #pragma unroll
    for (int mt = 0; mt < 4; ++mt) {
        #pragma unroll
        for (int r = 0; r < 4; ++r) {
            int i = mt * 16 + lg * 4 + r;
            int ih = i / 7, iw = i - ih * 7;
            int gh = wh * 7 + ih, gw = wwc * 7 + iw;
            int rhI = gh < 49 ? 0 : (gh < 53 ? 1 : 2);
            int rwI = gw < 49 ? 0 : (gw < 53 ? 1 : 2);
            int ridI = rhI * 3 + rwI;
            bool ivalid = (i < NTOK);
            float vals[4];
            float vmax = -1e30f;
            #pragma unroll
            for (int nt = 0; nt < 4; ++nt) {
                int j = nt * 16 + lr;
                float v = -1e30f;
                if (ivalid && j < NTOK) {
                    int rpi = (ih - jh[nt] + 6) * 13 + (iw - jw[nt] + 6);
                    float bv = bf2f(rpbs[rpi * 8 + hh]);
                    float msk = (ridI == ridJ[nt]) ? 0.f : -100.f;
                    v = sc[mt][nt][r] * scale + bv + msk;
                }
                vals[nt] = v;
                vmax = fmaxf(vmax, v);
            }
            #pragma unroll
            for (int off = 1; off < 16; off <<= 1)
                vmax = fmaxf(vmax, __shfl_xor(vmax, off));
            float s = 0.f;
            unsigned short pb[4];
            #pragma unroll
            for (int nt = 0; nt < 4; ++nt) {
                float e = (vals[nt] > -1e29f) ? __expf(vals[nt] - vmax) : 0.f;
                s += e;
                pb[nt] = f2bf(e);
            }
            #pragma unroll
            for (int off = 1; off < 16; off <<= 1)
                s += __shfl_xor(s, off);
            rowrcp[mt][r] = 1.f / s;
            #pragma unroll
            for (int nt = 0; nt < 4; ++nt) {
                int j = nt * 16 + lr;
                Pm[(i * 64 + j) ^ ((i & 7) << 3)] = pb[nt];
            }
        }
    }

    f32x4 o[4][2];
    #pragma unroll
    for (int mt = 0; mt < 4; ++mt)
        #pragma unroll
        for (int nt = 0; nt < 2; ++nt)
            o[mt][nt] = (f32x4){0.f, 0.f, 0.f, 0.f};
    #pragma unroll
    for (int ks = 0; ks < 2; ++ks) {
        bf16x8 ap[4], bv2[2];
        #pragma unroll
        for (int mt = 0; mt < 4; ++mt) {
            int row = mt * 16 + lr;
            ap[mt] = *(bf16x8*)&Pm[(row * 64 + ks * 32 + lg * 8) ^ ((row & 7) << 3)];
        }
        #pragma unroll
        for (int nt = 0; nt < 2; ++nt) {
            int n = nt * 16 + lr;
            bv2[nt] = *(bf16x8*)&Vt[(n * 64 + ks * 32 + lg * 8) ^ ((n & 7) << 3)];
        }
        #pragma unroll
        for (int mt = 0; mt < 4; ++mt)
            #pragma unroll
            for (int nt = 0; nt < 2; ++nt)
                o[mt][nt] = __builtin_amdgcn_mfma_f32_16x16x32_bf16(ap[mt], bv2[nt], o[mt][nt], 0, 0, 0);
    }

    // in-place store into the Q columns of this (window, head)
    #pragma unroll
    for (int mt = 0; mt < 4; ++mt)
        #pragma unroll
        for (int r = 0; r < 4; ++r) {
            int i = mt * 16 + lg * 4 + r;
            if (i < NTOK) {
                float rc = rowrcp[mt][r];
                #pragma unroll
                for (int nt = 0; nt < 2; ++nt) {
                    int d = nt * 16 + lr;
                    qkv[((size_t)b_ * NTOK + i) * 768 + hh * HDc + d] = f2bf(o[mt][nt][r] * rc);
                }
            }
        }
}

// ------------------------------------------------ fused LN2 + MLP v9 + residual + NCHW out
// 64 rows/block, 512 threads (8 waves). Wave (wm=w>>1) owns 16 rows, (wn=w&1) a 128-col half.
// Halved accumulator state (gfx950 unified VGPR/AGPR budget). w1s+w2s LDS-staged with
// chunk-ahead register prefetch; transposed fc1 -> packed b64 hid writes; hid 8KB.
// LDS 72KB. 3 barriers/chunk. 64 | Lc: no image straddle in epilogue.
// [FINAL session config: 515us total, twice replicated. MLP ~240us is a structural floor
//  of this kernel class — 7 independent levers (LDS, regs, barriers, routing, setprio)
//  all measured 238-273us, none beating v9's 238.]
#define HIDX(m, c) (((m) * 64 + (c)) ^ (((m) & 7) << 3))
__global__ __launch_bounds__(512) void k_mlp_fused(const unsigned short* __restrict__ xs,
                                                   const float* __restrict__ n2w,
                                                   const float* __restrict__ n2b,
                                                   const unsigned short* __restrict__ w1t,
                                                   const float* __restrict__ b1,
                                                   const unsigned short* __restrict__ w2t,
                                                   const float* __restrict__ b2,
                                                   float* __restrict__ out) {
    __shared__ unsigned short w1s[16384];   // 32KB
    __shared__ unsigned short w2s[16384];   // 32KB
    __shared__ unsigned short hid[4096];    // 64m x 64c, swizzled (8KB)
    int t = threadIdx.x;
    int l = t & 63, w = t >> 6;
    int wm = w >> 1, wn = w & 1;
    int lr = l & 15, lg = l >> 4;
    int m0 = blockIdx.x * 64;

    // ---- Phase A: LN2 into registers (row = wm*16+lr; 4 lanes (lg) per row)
    bf16x8 xf[8];
    {
        int row = m0 + wm * 16 + lr;
        const unsigned short* xrow = xs + (size_t)row * Cc;
        u16x8 raw[8];
        float sum = 0.f, sq = 0.f;
        #pragma unroll
        for (int ks = 0; ks < 8; ++ks) {
            raw[ks] = *(const u16x8*)(xrow + ks * 32 + lg * 8);
            #pragma unroll
            for (int e = 0; e < 8; ++e) {
                float f = bf2f(raw[ks][e]);
                sum += f; sq += f * f;
            }
        }
        sum += __shfl_xor(sum, 16); sq += __shfl_xor(sq, 16);
        sum += __shfl_xor(sum, 32); sq += __shfl_xor(sq, 32);
        float mu = sum / Cc;
        float rsg = rsqrtf(sq / Cc - mu * mu + EPS);
        #pragma unroll
        for (int ks = 0; ks < 8; ++ks) {
            #pragma unroll
            for (int e = 0; e < 8; ++e) {
                int c = ks * 32 + lg * 8 + e;
                float nv = (bf2f(raw[ks][e]) - mu) * rsg * n2w[c] + n2b[c];
                ((unsigned short*)&xf[ks])[e] = f2bf(nv);
            }
        }
    }

    f32x4 acc2[8];
    #pragma unroll
    for (int nf = 0; nf < 8; ++nf)
        acc2[nf] = (f32x4){0.f, 0.f, 0.f, 0.f};

    // prefetch chunk 0 (both weight buffers)
    u16x8 p1[4], p2[4];
    #pragma unroll
    for (int i = 0; i < 4; ++i) {
        int idx = (i * 512 + t) * 8;
        p1[i] = *(const u16x8*)(w1t + idx);
        p2[i] = *(const u16x8*)(w2t + idx);
    }

    for (int ch = 0; ch < 16; ++ch) {
        // ---- commit prefetched chunk to LDS
        #pragma unroll
        for (int i = 0; i < 4; ++i) {
            int idx = (i * 512 + t) * 8;
            *(u16x8*)&w1s[idx] = p1[i];
            *(u16x8*)&w2s[idx] = p2[i];
        }
        __syncthreads();
        // ---- issue prefetch for chunk ch+1 (completes under fc1+fc2)
        if (ch < 15) {
            const unsigned short* n1 = w1t + (ch + 1) * 16384;
            const unsigned short* n2 = w2t + (ch + 1) * 16384;
            #pragma unroll
            for (int i = 0; i < 4; ++i) {
                int idx = (i * 512 + t) * 8;
                p1[i] = *(const u16x8*)(n1 + idx);
                p2[i] = *(const u16x8*)(n2 + idx);
            }
        }
        // ---- fc1 (transposed): D[h][m]; wave: h-tiles {2wn,2wn+1}, its own m-frag (wm)
        {
            f32x4 acc1[2];
            acc1[0] = (f32x4){0.f, 0.f, 0.f, 0.f};
            acc1[1] = (f32x4){0.f, 0.f, 0.f, 0.f};
            #pragma unroll
            for (int ks = 0; ks < 8; ++ks) {
                #pragma unroll
                for (int ht = 0; ht < 2; ++ht) {
                    bf16x8 wfr = *(const bf16x8*)&w1s[(wn * 2 + ht) * 4096 + ks * 512 + l * 8];
                    acc1[ht] = __builtin_amdgcn_mfma_f32_16x16x32_bf16(wfr, xf[ks], acc1[ht], 0, 0, 0);
                }
            }
            #pragma unroll
            for (int ht = 0; ht < 2; ++ht) {
                float b1v[4];
                #pragma unroll
                for (int r = 0; r < 4; ++r)
                    b1v[r] = b1[ch * 64 + (wn * 2 + ht) * 16 + lg * 4 + r];
                u16x4 pk;
                #pragma unroll
                for (int r = 0; r < 4; ++r)
                    pk[r] = f2bf(fmaxf(acc1[ht][r] + b1v[r], 0.f));
                int m = wm * 16 + lr;
                int off = m * 64 + ((((wn * 2 + ht) * 16) + lg * 4) ^ ((m & 7) << 3));
                *(u16x4*)&hid[off] = pk;
            }
        }
        __syncthreads();
        // ---- fc2 partial over this chunk's 64 h-dims (w2 from LDS)
        {
            bf16x8 a[2];
            #pragma unroll
            for (int ks = 0; ks < 2; ++ks) {
                int m = wm * 16 + lr;
                a[ks] = *(const bf16x8*)&hid[HIDX(m, ks * 32 + lg * 8)];
            }
            #pragma unroll
            for (int ks = 0; ks < 2; ++ks)
                #pragma unroll
                for (int nf = 0; nf < 8; ++nf) {
                    int nt = wn * 8 + nf;
                    bf16x8 bfr = *(const bf16x8*)&w2s[(nt * 2 + ks) * 512 + l * 8];
                    acc2[nf] = __builtin_amdgcn_mfma_f32_16x16x32_bf16(a[ks], bfr, acc2[nf], 0, 0, 0);
                }
        }
        __syncthreads();
    }

    // ---- epilogue: + b2 + residual, NCHW store (64 | Lc: no image straddle)
    int b0i = m0 / Lc, l0 = m0 % Lc;
    #pragma unroll
    for (int nf = 0; nf < 8; ++nf) {
        int c = wn * 128 + nf * 16 + lr;
        float b2c = b2[c];
        #pragma unroll
        for (int r = 0; r < 4; ++r) {
            int m = wm * 16 + lg * 4 + r;
            float res = bf2f(xs[(size_t)(m0 + m) * Cc + c]);
            out[((size_t)b0i * Cc + c) * Lc + l0 + m] = acc2[nf][r] + b2c + res;
        }
    }
}

// ----------------------------------------------------------------- launch
extern "C" void kernel_launch(void* const* d_in, const int* in_sizes, int n_in,
                              void* d_out, int out_size, void* d_ws, size_t ws_size,
                              hipStream_t stream) {
    const float* x      = (const float*)d_in[0];
    const float* qkv_w  = (const float*)d_in[1];
    const float* q_bias = (const float*)d_in[2];
    const float* v_bias = (const float*)d_in[3];
    const float* proj_w = (const float*)d_in[4];
    const float* proj_b = (const float*)d_in[5];
    const float* rpb    = (const float*)d_in[6];
    const float* n1w    = (const float*)d_in[7];
    const float* n1b    = (const float*)d_in[8];
    const float* n2w    = (const float*)d_in[9];
    const float* n2b    = (const float*)d_in[10];
    const float* w1     = (const float*)d_in[11];
    const float* b1     = (const float*)d_in[12];
    const float* w2     = (const float*)d_in[13];
    const float* b2     = (const float*)d_in[14];

    char* ws = (char*)d_ws;
    const size_t SZ_BF16 = (size_t)Mrows * Cc * 2;
    unsigned short* xw      = (unsigned short*)ws;          // xw, later xs (b,l,c)
    float*          qkvb    = (float*)(ws + SZ_BF16);
    unsigned short* qkv_wb  = (unsigned short*)(ws + SZ_BF16 + 3072);
    unsigned short* proj_wb = qkv_wb + 196608;
    unsigned short* w1t     = proj_wb + 65536;
    unsigned short* w2t     = w1t + 262144;

    // d_out scratch (exact fit; fully overwritten by k_mlp_fused):
    //   [0, 77,070,336)             qkv_s bf16 (50176 x 768); attn writes output in place over Q cols
    //   [77,070,336, 102,760,448)   xres bf16 (50176 x 256)
    unsigned short* qkv_s  = (unsigned short*)d_out;
    unsigned short* xres_s = qkv_s + (size_t)ROWS_G * 768;

    k_prep<<<1024, 256, 0, stream>>>(qkv_w, proj_w, w1, w2, q_bias, v_bias,
                                     qkv_wb, proj_wb, w1t, w2t, qkvb);

    for (int g = 0; g < NGRP; ++g) {
        unsigned short* xw_g = xw + (size_t)g * ROWS_G * Cc;
        k_ln1_part<<<GIMG * Hc, 256, 0, stream>>>(x, n1w, n1b, xw, xres_s, g * GIMG);
        k_gemm_mfma<<<dim3(ROWS_G / 128, 768 / 128), 256, 0, stream>>>(
            xw_g, qkv_wb, qkvb, qkv_s, 256, 768);
        k_attn<<<WIN_G * NHc / 4, 256, 0, stream>>>(qkv_s, rpb);
        k_gemm_proj<<<dim3(ROWS_G / 128, 2), 256, 0, stream>>>(
            qkv_s, proj_wb, proj_b, xres_s, xw_g);
    }

    k_mlp_fused<<<Mrows / 64, 512, 0, stream>>>(xw, n2w, n2b, w1t, b1, w2t, b2,
                                                (float*)d_out);
}